// Round 4
// baseline (713.455 us; speedup 1.0000x reference)
//
#include <hip/hip_runtime.h>

namespace {

constexpr int T    = 512;   // sequence length
constexpr int H    = 64;    // hidden units
constexpr int TPB  = 256;   // 4 waves, 1 per SIMD (1 block/CU)
constexpr int BPB  = 8;     // batches per block
constexpr int HSTR = 68;    // h row stride (floats); 68*4B keeps b128 aligned, banks spread

// DPP quad_perm controls: lane i reads lane ((ctrl >> 2i) & 3) within its quad
constexpr int QP_R1 = 0x93;  // perm [3,0,1,2]: lane q <- lane (q-1)&3
constexpr int QP_R2 = 0x4E;  // perm [2,3,0,1]: lane q <- lane (q-2)&3
constexpr int QP_R3 = 0x39;  // perm [1,2,3,0]: lane q <- lane (q+1)&3

__device__ __forceinline__ float fsig(float x) {
  return __builtin_amdgcn_rcpf(1.0f + __expf(-x));
}
__device__ __forceinline__ float ftanh(float x) {
  return fmaf(-2.0f, __builtin_amdgcn_rcpf(1.0f + __expf(2.0f * x)), 1.0f);
}
template <int CTRL>
__device__ __forceinline__ float qrot(float v) {
  return __int_as_float(__builtin_amdgcn_update_dpp(
      0, __float_as_int(v), CTRL, 0xf, 0xf, true));
}
__device__ __forceinline__ float dot4(float4 w, float4 h, float a) {
  a = fmaf(w.x, h.x, a); a = fmaf(w.y, h.y, a);
  a = fmaf(w.z, h.z, a); return fmaf(w.w, h.w, a);
}
// dot4 with no incoming accumulator (starts with a mul — saves the zero-init mov)
__device__ __forceinline__ float dot4i(float4 w, float4 h) {
  return fmaf(w.w, h.w, fmaf(w.z, h.z, fmaf(w.y, h.y, w.x * h.x)));
}
// Pin into AGPRs: global loads cannot be rematerialized into AGPRs, and with
// the unified gfx950 RF, VALU reads AGPR sources directly (CDNA2+).
// (R3 evidence: "+v" pin -> allocator spilled W to scratch; FETCH stayed 2.4GB.)
__device__ __forceinline__ void pina4(float4& v) {
  asm volatile("" : "+a"(v.x), "+a"(v.y), "+a"(v.z), "+a"(v.w));
}
__device__ __forceinline__ void pina(float& v) { asm volatile("" : "+a"(v)); }

// grid 256 x block 256 (1 block/CU). Block = 8 batches x 64 units.
// Lane: q = tid&3 (k-quarter), bg = (tid>>2)&1 (batch group of 4),
//       us = tid>>3 in [0,32) (unit-slot -> units 2us, 2us+1).
// Per lane: W_hh rows {g*64 + 2us + uu} x k in [16q,16q+16) = 128 floats (AGPR).
// Rotation trick: acc[r][j] accumulates the partial for batch 4bg + (q+j)&3,
// so the quad reduction is 3 quad_perm DPP adds per row, zero selects.
__global__ __launch_bounds__(TPB, 1)
void lstm_fused(const float* __restrict__ xg,
                const float* __restrict__ W_ih,
                const float* __restrict__ W_hh,
                const float* __restrict__ b_ih,
                const float* __restrict__ b_hh,
                const float* __restrict__ fc1_w,
                const float* __restrict__ fc1_b,
                const float* __restrict__ fc2_w,
                const float* __restrict__ fc2_b,
                float* __restrict__ out)
{
  __shared__ __align__(16) float hs0[BPB * HSTR];   // h double-buffer
  __shared__ __align__(16) float hs1[BPB * HSTR];
  __shared__ __align__(16) float xs[BPB][T + 4];    // x staged; stride 516 spreads banks
  __shared__ float zs[BPB][16];

  const int tid = threadIdx.x;
  const int b0  = blockIdx.x * BPB;
  const int q   = tid & 3;
  const int bg  = (tid >> 2) & 1;
  const int us  = tid >> 3;          // 0..31
  const int bown = 4 * bg + q;       // this lane's batch (0..7 within block)

  // ---- stage x: 8 batches x 512 floats, coalesced float4 ----
  for (int i = tid; i < BPB * T / 4; i += TPB) {
    const int xb = i >> 7, tq = i & 127;
    float4 v = ((const float4*)(xg + (size_t)(b0 + xb) * T))[tq];
    *(float4*)&xs[xb][tq * 4] = v;
  }
  // ---- zero h buffers ----
  for (int i = tid; i < BPB * HSTR; i += TPB) { hs0[i] = 0.0f; hs1[i] = 0.0f; }

  // ---- per-lane W tile: 8 rows x 16 k = 32 float4 = 128 AGPRs ----
  float4 wf[8][4];                   // [r = g*2+uu][kk]
#pragma unroll
  for (int g = 0; g < 4; ++g) {
#pragma unroll
    for (int uu = 0; uu < 2; ++uu) {
      const int row = g * H + 2 * us + uu;
      const float* src = W_hh + row * H + q * 16;
#pragma unroll
      for (int kk = 0; kk < 4; ++kk) {
        wf[g * 2 + uu][kk] = *(const float4*)(src + 4 * kk);
        pina4(wf[g * 2 + uu][kk]);
      }
    }
  }
  float wih[8], bia[8];
#pragma unroll
  for (int g = 0; g < 4; ++g) {
#pragma unroll
    for (int uu = 0; uu < 2; ++uu) {
      const int row = g * H + 2 * us + uu;
      wih[g * 2 + uu] = W_ih[row];
      bia[g * 2 + uu] = b_ih[row] + b_hh[row];
      pina(wih[g * 2 + uu]); pina(bia[g * 2 + uu]);
    }
  }

  // per-lane h read offsets for batch (q+j)&3 of its group, k-slice 16q
  int off[4];
#pragma unroll
  for (int j = 0; j < 4; ++j) off[j] = (4 * bg + ((q + j) & 3)) * HSTR + 16 * q;
  const int hwoff = bown * HSTR + 2 * us;   // write slot: units 2us,2us+1 (float2)
  const float* xq = &xs[bown][0];

  float c0 = 0.0f, c1 = 0.0f;

  __syncthreads();

#define LSTM_STEP(HSRC, HDST, TT)                                              \
  {                                                                            \
    const float xt = xq[(TT)];                                                 \
    float acc[8][4];                                                           \
    _Pragma("unroll") for (int r = 0; r < 8; ++r)                              \
      acc[r][0] = fmaf(xt, wih[r], bia[r]); /* bias + x*W_ih folded into j=0 */\
    _Pragma("unroll") for (int j = 0; j < 4; ++j) {                            \
      const float* hb = (HSRC) + off[j];                                       \
      const float4 h0 = *(const float4*)(hb + 0);                              \
      const float4 h1 = *(const float4*)(hb + 4);                              \
      const float4 h2 = *(const float4*)(hb + 8);                              \
      const float4 h3 = *(const float4*)(hb + 12);                             \
      _Pragma("unroll") for (int r = 0; r < 8; ++r) {                          \
        float a = (j == 0) ? dot4(wf[r][0], h0, acc[r][0])                     \
                           : dot4i(wf[r][0], h0);                              \
        a = dot4(wf[r][1], h1, a);                                             \
        a = dot4(wf[r][2], h2, a);                                             \
        a = dot4(wf[r][3], h3, a);                                             \
        acc[r][j] = a;                                                         \
      }                                                                        \
    }                                                                          \
    float red[8];                                                              \
    _Pragma("unroll") for (int r = 0; r < 8; ++r) {                            \
      float s = acc[r][0];                                                     \
      s += qrot<QP_R1>(acc[r][1]);                                             \
      s += qrot<QP_R2>(acc[r][2]);                                             \
      s += qrot<QP_R3>(acc[r][3]);                                             \
      red[r] = s;                                                              \
    }                                                                          \
    const float i0 = fsig(red[0]),  i1 = fsig(red[1]);                         \
    const float f0 = fsig(red[2]),  f1 = fsig(red[3]);                         \
    const float g0 = ftanh(red[4]), g1 = ftanh(red[5]);                        \
    const float o0 = fsig(red[6]),  o1 = fsig(red[7]);                         \
    c0 = fmaf(f0, c0, i0 * g0);                                                \
    c1 = fmaf(f1, c1, i1 * g1);                                                \
    const float hn0 = o0 * ftanh(c0);                                          \
    const float hn1 = o1 * ftanh(c1);                                          \
    *(float2*)((HDST) + hwoff) = make_float2(hn0, hn1);                        \
    __syncthreads();                                                           \
  }

  for (int t = 0; t < T; t += 2) {
    LSTM_STEP(hs0, hs1, t);
    LSTM_STEP(hs1, hs0, t + 1);
  }
#undef LSTM_STEP

  // final h in hs0 (T even). Head: relu(h@fc1^T+b1) @ fc2^T + b2
  if (tid < BPB * 16) {
    const int bq = tid >> 4;
    const int j2 = tid & 15;
    float s = fc1_b[j2];
    const float* fw = fc1_w + j2 * H;
#pragma unroll
    for (int k = 0; k < H; ++k) s = fmaf(hs0[bq * HSTR + k], fw[k], s);
    s = fmaxf(s, 0.0f);
    zs[bq][j2] = s * fc2_w[j2];
  }
  __syncthreads();
  if (tid < BPB) {
    float s = fc2_b[0];
#pragma unroll
    for (int j = 0; j < 16; ++j) s += zs[tid][j];
    out[b0 + tid] = s;
  }
}

}  // namespace

extern "C" void kernel_launch(void* const* d_in, const int* in_sizes, int n_in,
                              void* d_out, int out_size, void* d_ws, size_t ws_size,
                              hipStream_t stream) {
  const float* xg    = (const float*)d_in[0];
  const float* W_ih  = (const float*)d_in[1];
  const float* W_hh  = (const float*)d_in[2];
  const float* b_ih  = (const float*)d_in[3];
  const float* b_hh  = (const float*)d_in[4];
  const float* fc1_w = (const float*)d_in[5];
  const float* fc1_b = (const float*)d_in[6];
  const float* fc2_w = (const float*)d_in[7];
  const float* fc2_b = (const float*)d_in[8];
  float* out = (float*)d_out;

  dim3 grid(2048 / BPB);   // 256 blocks -> 1 per CU
  dim3 block(TPB);
  hipLaunchKernelGGL(lstm_fused, grid, block, 0, stream,
                     xg, W_ih, W_hh, b_ih, b_hh, fc1_w, fc1_b, fc2_w, fc2_b, out);
}

// Round 5
// 449.124 us; speedup vs baseline: 1.5885x; 1.5885x over previous
//
#include <hip/hip_runtime.h>

namespace {

typedef __attribute__((ext_vector_type(8))) short short8;   // MFMA A/B frag (8 bf16)
typedef __attribute__((ext_vector_type(4))) float floatx4;  // MFMA C/D frag

constexpr int T    = 512;
constexpr int H    = 64;
constexpr int TPB  = 256;   // 4 waves
constexpr int MB   = 16;    // batches per block (MFMA M/N=16)
constexpr int HBU  = 200;   // h-ext row stride in ushorts (400 B = 25*16B; banks: 100%32=4)
constexpr int XSTR = 516;   // xs row stride (floats); 516%32=4 -> 2-way on xt reads (free)
constexpr int FSTR = 68;    // hf32 row stride (floats)

__device__ __forceinline__ ushort f2bf(float x) {  // fp32 -> bf16 RN-even (finite inputs)
  unsigned u = __float_as_uint(x);
  unsigned r = u + 0x7fffu + ((u >> 16) & 1u);
  return (ushort)(r >> 16);
}
__device__ __forceinline__ float bf2f(ushort h) {
  return __uint_as_float(((unsigned)h) << 16);
}
__device__ __forceinline__ float fsig(float x) {
  return __builtin_amdgcn_rcpf(1.0f + __expf(-x));
}
__device__ __forceinline__ float ftanh(float x) {
  return fmaf(-2.0f, __builtin_amdgcn_rcpf(1.0f + __expf(2.0f * x)), 1.0f);
}

// D = A*B + C per step:  A = W_ext tile (16 gate-rows x K), B = h_ext (K x 16 batches),
// D[gate-row][batch].  Split: K_ext=192 = [W_hi|W_hi|W_lo] x [h_hi|h_lo|h_hi].
// Layouts (verified, guide §3): A[m=lane&15][k=8*(lane>>4)+j]; B[k=8*(lane>>4)+j][n=lane&15];
// D col=lane&15 (batch), row=4*(lane>>4)+reg (within 16-row tile).
// Wave j owns N-tiles {j, j+4, j+8, j+12} -> lane holds i,f,g,o of units 16j+4kg+r, batch n.
__global__ __launch_bounds__(TPB, 1)
void lstm_mfma(const float* __restrict__ xg,
               const float* __restrict__ W_ih,
               const float* __restrict__ W_hh,
               const float* __restrict__ b_ih,
               const float* __restrict__ b_hh,
               const float* __restrict__ fc1_w,
               const float* __restrict__ fc1_b,
               const float* __restrict__ fc2_w,
               const float* __restrict__ fc2_b,
               float* __restrict__ out)
{
  __shared__ __align__(16) ushort hA[MB * HBU];   // h-ext bf16 double-buffer
  __shared__ __align__(16) ushort hB[MB * HBU];   // cols: [0,64)=hi, [64,128)=lo, [128,192)=hi
  __shared__ __align__(16) float  xs[MB * XSTR];
  __shared__ __align__(16) float  hf[MB * FSTR];  // h fp32 (for the head)
  __shared__ float zs[MB][16];

  const int tid  = threadIdx.x;
  const int b0   = blockIdx.x * MB;
  const int lane = tid & 63;
  const int wj   = tid >> 6;     // wave 0..3
  const int n    = lane & 15;    // batch col (B/D) and A-frag row
  const int kg   = lane >> 4;    // k-group (A/B), row-quad (D)

  // ---- stage x (coalesced float4) ----
  for (int i = tid; i < MB * T / 4; i += TPB) {
    const int xb = i >> 7, tq = i & 127;
    float4 v = ((const float4*)(xg + (size_t)(b0 + xb) * T))[tq];
    *(float4*)&xs[xb * XSTR + tq * 4] = v;
  }
  // ---- zero h buffers (h0 = 0) ----
  for (int i = tid; i < MB * HBU; i += TPB) { hA[i] = 0; hB[i] = 0; }

  // ---- static W fragments: g=0..3 -> gates i,f,g,o; tile rows 64g+16wj+[0,16) ----
  short8 whi0[4], whi1[4], wlo0[4], wlo1[4];
  float bia[4][4], wih[4][4];
#pragma unroll
  for (int g = 0; g < 4; ++g) {
    const int arow = 64 * g + 16 * wj + n;          // this lane's A-frag row
    const float* wr = W_hh + arow * H + 8 * kg;     // k slice [8kg, 8kg+8) and +32
    const float4 p0 = *(const float4*)(wr + 0);
    const float4 p1 = *(const float4*)(wr + 4);
    const float4 p2 = *(const float4*)(wr + 32);
    const float4 p3 = *(const float4*)(wr + 36);
    const float v0[8] = {p0.x, p0.y, p0.z, p0.w, p1.x, p1.y, p1.z, p1.w};
    const float v1[8] = {p2.x, p2.y, p2.z, p2.w, p3.x, p3.y, p3.z, p3.w};
#pragma unroll
    for (int j = 0; j < 8; ++j) {
      const ushort h0 = f2bf(v0[j]);
      whi0[g][j] = (short)h0;
      wlo0[g][j] = (short)f2bf(v0[j] - bf2f(h0));   // exact remainder, then RN
      const ushort h1 = f2bf(v1[j]);
      whi1[g][j] = (short)h1;
      wlo1[g][j] = (short)f2bf(v1[j] - bf2f(h1));
    }
    const int drow = 64 * g + 16 * wj + 4 * kg;     // this lane's D rows (+r)
#pragma unroll
    for (int r = 0; r < 4; ++r) {
      bia[g][r] = b_ih[drow + r] + b_hh[drow + r];
      wih[g][r] = W_ih[drow + r];
    }
  }

  const int Ubase = 16 * wj + 4 * kg;   // this lane's 4 units
  float c[4] = {0.0f, 0.0f, 0.0f, 0.0f};

  __syncthreads();

#define STEP(HR, HW, TT)                                                       \
  {                                                                            \
    const float xt = xs[n * XSTR + (TT)];                                      \
    floatx4 acc[4];                                                            \
    _Pragma("unroll") for (int g = 0; g < 4; ++g)                              \
      _Pragma("unroll") for (int r = 0; r < 4; ++r)                            \
        acc[g][r] = fmaf(xt, wih[g][r], bia[g][r]);                            \
    const ushort* hb = (HR) + n * HBU + 8 * kg;                                \
    const short8 f0 = *(const short8*)(hb + 0);    /* h_hi k 0..31  */         \
    const short8 f1 = *(const short8*)(hb + 32);   /* h_hi k 32..63 */         \
    const short8 f2 = *(const short8*)(hb + 64);   /* h_lo k 0..31  */         \
    const short8 f3 = *(const short8*)(hb + 96);   /* h_lo k 32..63 */         \
    const short8 f4 = *(const short8*)(hb + 128);  /* h_hi dup      */         \
    const short8 f5 = *(const short8*)(hb + 160);                              \
    _Pragma("unroll") for (int g = 0; g < 4; ++g) {                            \
      acc[g] = __builtin_amdgcn_mfma_f32_16x16x32_bf16(whi0[g], f0, acc[g], 0, 0, 0); \
      acc[g] = __builtin_amdgcn_mfma_f32_16x16x32_bf16(whi1[g], f1, acc[g], 0, 0, 0); \
      acc[g] = __builtin_amdgcn_mfma_f32_16x16x32_bf16(whi0[g], f2, acc[g], 0, 0, 0); \
      acc[g] = __builtin_amdgcn_mfma_f32_16x16x32_bf16(whi1[g], f3, acc[g], 0, 0, 0); \
      acc[g] = __builtin_amdgcn_mfma_f32_16x16x32_bf16(wlo0[g], f4, acc[g], 0, 0, 0); \
      acc[g] = __builtin_amdgcn_mfma_f32_16x16x32_bf16(wlo1[g], f5, acc[g], 0, 0, 0); \
    }                                                                          \
    float hnew[4];                                                             \
    _Pragma("unroll") for (int r = 0; r < 4; ++r) {                            \
      const float ig = fsig(acc[0][r]);                                        \
      const float fg = fsig(acc[1][r]);                                        \
      const float gg = ftanh(acc[2][r]);                                       \
      const float og = fsig(acc[3][r]);                                        \
      c[r] = fmaf(fg, c[r], ig * gg);                                          \
      hnew[r] = og * ftanh(c[r]);                                              \
    }                                                                          \
    const ushort u0 = f2bf(hnew[0]), u1 = f2bf(hnew[1]);                       \
    const ushort u2 = f2bf(hnew[2]), u3 = f2bf(hnew[3]);                       \
    const ushort4 hiv = make_ushort4(u0, u1, u2, u3);                          \
    const ushort4 lov = make_ushort4(f2bf(hnew[0] - bf2f(u0)),                 \
                                     f2bf(hnew[1] - bf2f(u1)),                 \
                                     f2bf(hnew[2] - bf2f(u2)),                 \
                                     f2bf(hnew[3] - bf2f(u3)));                \
    ushort* hw = (HW) + n * HBU + Ubase;                                       \
    *(ushort4*)(hw + 0)   = hiv;                                               \
    *(ushort4*)(hw + 64)  = lov;                                               \
    *(ushort4*)(hw + 128) = hiv;                                               \
    *(float4*)&hf[n * FSTR + Ubase] =                                          \
        make_float4(hnew[0], hnew[1], hnew[2], hnew[3]);                       \
    __syncthreads();                                                           \
  }

  for (int t = 0; t < T; t += 2) {
    STEP(hA, hB, t);
    STEP(hB, hA, t + 1);
  }
#undef STEP

  // ---- head: z = relu(h@fc1^T+b1); out = z@fc2^T + b2 ----
  {
    const int bq = tid >> 4, j2 = tid & 15;   // 16 batches x 16 hidden2 = 256 threads
    float s = fc1_b[j2];
    const float* fw = fc1_w + j2 * H;
#pragma unroll
    for (int k = 0; k < H; ++k) s = fmaf(hf[bq * FSTR + k], fw[k], s);
    s = fmaxf(s, 0.0f);
    zs[bq][j2] = s * fc2_w[j2];
  }
  __syncthreads();
  if (tid < MB) {
    float s = fc2_b[0];
#pragma unroll
    for (int j = 0; j < 16; ++j) s += zs[tid][j];
    out[b0 + tid] = s;
  }
}

}  // namespace

extern "C" void kernel_launch(void* const* d_in, const int* in_sizes, int n_in,
                              void* d_out, int out_size, void* d_ws, size_t ws_size,
                              hipStream_t stream) {
  const float* xg    = (const float*)d_in[0];
  const float* W_ih  = (const float*)d_in[1];
  const float* W_hh  = (const float*)d_in[2];
  const float* b_ih  = (const float*)d_in[3];
  const float* b_hh  = (const float*)d_in[4];
  const float* fc1_w = (const float*)d_in[5];
  const float* fc1_b = (const float*)d_in[6];
  const float* fc2_w = (const float*)d_in[7];
  const float* fc2_b = (const float*)d_in[8];
  float* out = (float*)d_out;

  dim3 grid(2048 / MB);   // 128 blocks
  dim3 block(TPB);
  hipLaunchKernelGGL(lstm_mfma, grid, block, 0, stream,
                     xg, W_ih, W_hh, b_ih, b_hh, fc1_w, fc1_b, fc2_w, fc2_b, out);
}